// Round 4
// baseline (579.780 us; speedup 1.0000x reference)
//
#include <hip/hip_runtime.h>
#include <hip/hip_fp16.h>
#include <math.h>

// Problem constants
#define BATCH 256
#define CIN 3
#define HW 128
#define OC 16
#define POOLED 63          // pooled spatial dim
#define FEAT 63504         // OC*63*63
#define NH 256
#define FANIN 512
#define NO 10
#define CHW (CIN*HW*HW)    // 49152

// packed f16 max — ROCm 7.2 lacks __hmax2 on gfx950; this pattern-matches to
// v_pk_max_f16.
__device__ inline __half2 h2max(__half2 a, __half2 b) {
    return __halves2half2(__hmax(__low2half(a),  __low2half(b)),
                          __hmax(__high2half(a), __high2half(b)));
}

// ---- Kernel 0: prep — duplicate conv weights/bias into __half2 {w,w} ----------
__global__ __launch_bounds__(512) void prep_kernel(const float* __restrict__ cw,
                                                   const float* __restrict__ cb,
                                                   __half2* __restrict__ w2,
                                                   __half2* __restrict__ b2) {
    const int t = threadIdx.x;
    if (t < OC * 27) {
        __half h = __float2half_rn(cw[t]);
        w2[t] = __halves2half2(h, h);
    } else if (t < OC * 27 + OC) {
        __half h = __float2half_rn(cb[t - OC * 27]);
        b2[t - OC * 27] = __halves2half2(h, h);
    }
}

// ---- Kernel 1: transpose+convert inputs (B, CHW) fp32 -> (CHW, B) f16 ----------
__global__ __launch_bounds__(256) void transpose_f16_kernel(const float* __restrict__ in,
                                                            __half* __restrict__ outh) {
    __shared__ float tile[64][65];   // tile[b_local][f_local]
    const int f0 = blockIdx.x * 64;
    const int b0 = blockIdx.y * 64;
    const int t  = threadIdx.x;
    // read phase: float4 along f, coalesced 256B/wave
    {
        const int r  = t >> 4;          // 0..15
        const int cg = t & 15;          // 0..15
#pragma unroll
        for (int it = 0; it < 4; ++it) {
            const int bl = r + 16 * it;
            const float4 v = *(const float4*)&in[(size_t)(b0 + bl) * CHW + f0 + cg * 4];
            tile[bl][cg * 4 + 0] = v.x;
            tile[bl][cg * 4 + 1] = v.y;
            tile[bl][cg * 4 + 2] = v.z;
            tile[bl][cg * 4 + 3] = v.w;
        }
    }
    __syncthreads();
    // write phase: each thread packs 8 b's (4 half2) for one f row -> 16B store
    {
        const int bg = t & 7;           // 8 groups of 8 b
#pragma unroll
        for (int it = 0; it < 2; ++it) {
            const int fl = (t >> 3) + 32 * it;   // 0..63
            __half2 hv[4];
            hv[0] = __floats2half2_rn(tile[bg * 8 + 0][fl], tile[bg * 8 + 1][fl]);
            hv[1] = __floats2half2_rn(tile[bg * 8 + 2][fl], tile[bg * 8 + 3][fl]);
            hv[2] = __floats2half2_rn(tile[bg * 8 + 4][fl], tile[bg * 8 + 5][fl]);
            hv[3] = __floats2half2_rn(tile[bg * 8 + 6][fl], tile[bg * 8 + 7][fl]);
            *(float4*)&outh[(size_t)(f0 + fl) * BATCH + b0 + bg * 8] = *(float4*)hv;
        }
    }
}

// ---- Kernel 2: conv3x3 + bias + relu + maxpool2x2, packed-f16 (2 batches/lane) --
// inT2: (C,H,W, B/2) half2. featsT2: (FEAT, B/2) half2.
// Block: pooled row i, 3 pooled cols; t&127 = batch-pair, t>>7 = oc-group (8 ocs).
__global__ __launch_bounds__(256, 6) void conv_pool_kernel(const __half2* __restrict__ inT2,
                                                           const __half2* __restrict__ w2,
                                                           const __half2* __restrict__ b2,
                                                           __half2* __restrict__ featsT2) {
    const int t  = threadIdx.x;
    const int bp = t & 127;         // batch pair 0..127
    const int og = t >> 7;          // 0..1 oc group
    const int i  = blockIdx.y;      // pooled row
    const int jt = blockIdx.x;      // tile of 3 pooled cols
    const int yb = 2 * i;
    const __half2 zero2 = __float2half2_rn(0.0f);

    for (int s = 0; s < 3; ++s) {
        const int j  = jt * 3 + s;
        const int x0 = 2 * j;       // input cols x0..x0+3
        __half2 V[CIN][4][4];
#pragma unroll
        for (int c = 0; c < CIN; ++c)
#pragma unroll
            for (int dy = 0; dy < 4; ++dy)
#pragma unroll
                for (int dx = 0; dx < 4; ++dx)
                    V[c][dy][dx] =
                        inT2[(size_t)((c * HW + (yb + dy)) * HW + (x0 + dx)) * 128 + bp];

#pragma unroll
        for (int o = 0; o < 8; ++o) {
            const int oc = og * 8 + o;
            __half2 a00 = zero2, a01 = zero2, a10 = zero2, a11 = zero2;
#pragma unroll
            for (int c = 0; c < CIN; ++c)
#pragma unroll
                for (int ky = 0; ky < 3; ++ky)
#pragma unroll
                    for (int kx = 0; kx < 3; ++kx) {
                        const __half2 w = w2[oc * 27 + c * 9 + ky * 3 + kx];
                        a00 = __hfma2(V[c][ky    ][kx    ], w, a00);
                        a01 = __hfma2(V[c][ky    ][kx + 1], w, a01);
                        a10 = __hfma2(V[c][ky + 1][kx    ], w, a10);
                        a11 = __hfma2(V[c][ky + 1][kx + 1], w, a11);
                    }
            __half2 m = h2max(h2max(a00, a01), h2max(a10, a11));
            __half2 r = h2max(__hadd2(m, b2[oc]), zero2);
            featsT2[(size_t)(oc * 3969 + i * POOLED + j) * 128 + bp] = r;
        }
    }
}

// ---- Kernel 3: sparse hidden layer, f16 feats, transposed ----------------------
// Grid (NH, 2): block = (h, b-half). 1024 threads = 8 k-splits x 128 b.
__global__ __launch_bounds__(1024) void hidden_kernel(const __half* __restrict__ featsT_h,
                                                      const int* __restrict__ hidx,
                                                      const float* __restrict__ hw,
                                                      const float* __restrict__ hb,
                                                      float* __restrict__ hiddenT) {
    __shared__ int   sidx[FANIN];
    __shared__ float swt[FANIN];
    __shared__ float red[1024];
    const int h  = blockIdx.x;
    const int bh = blockIdx.y;
    const int t  = threadIdx.x;
    if (t < FANIN) {
        sidx[t] = hidx[h * FANIN + t];
        swt[t]  = hw[h * FANIN + t];
    }
    __syncthreads();
    const int b  = bh * 128 + (t & 127);
    const int ks = t >> 7;          // 0..7
    const int k0 = ks * 64;
    float acc = 0.f;
#pragma unroll 16
    for (int kk = 0; kk < 64; ++kk) {
        const int k = k0 + kk;
        acc += __half2float(featsT_h[(size_t)sidx[k] * BATCH + b]) * swt[k];
    }
    red[t] = acc;
    __syncthreads();
    if (t < 128) {
        float s = ((red[t] + red[t + 128]) + (red[t + 256] + red[t + 384]))
                + ((red[t + 512] + red[t + 640]) + (red[t + 768] + red[t + 896]));
        s += hb[h];
        hiddenT[h * BATCH + bh * 128 + t] = 1.0f / (1.0f + __expf(-s));
    }
}

// ---- Kernel 4: dense 256->10 output layer --------------------------------------
__global__ __launch_bounds__(256) void out_kernel(const float* __restrict__ hiddenT,
                                                  const float* __restrict__ ow,
                                                  const float* __restrict__ ob,
                                                  float* __restrict__ out) {
    const int o = blockIdx.x;       // 0..9
    const int b = threadIdx.x;      // 0..255
    float a0 = 0.f, a1 = 0.f, a2 = 0.f, a3 = 0.f;
#pragma unroll 16
    for (int h = 0; h < NH; h += 4) {
        a0 += hiddenT[(h + 0) * BATCH + b] * ow[o * NH + h + 0];
        a1 += hiddenT[(h + 1) * BATCH + b] * ow[o * NH + h + 1];
        a2 += hiddenT[(h + 2) * BATCH + b] * ow[o * NH + h + 2];
        a3 += hiddenT[(h + 3) * BATCH + b] * ow[o * NH + h + 3];
    }
    float acc = (a0 + a1) + (a2 + a3);
    out[b * NO + o] = 1.0f / (1.0f + __expf(-(acc + ob[o])));
}

extern "C" void kernel_launch(void* const* d_in, const int* in_sizes, int n_in,
                              void* d_out, int out_size, void* d_ws, size_t ws_size,
                              hipStream_t stream) {
    const float* inputs   = (const float*)d_in[0];
    const float* conv_w   = (const float*)d_in[1];
    const float* conv_b   = (const float*)d_in[2];
    const int*   hidden_i = (const int*)d_in[3];
    const float* hidden_w = (const float*)d_in[4];
    const float* hidden_b = (const float*)d_in[5];
    const float* out_w    = (const float*)d_in[6];
    const float* out_b    = (const float*)d_in[7];
    float* out = (float*)d_out;

    char* ws = (char*)d_ws;
    __half* inT_h    = (__half*)ws;                                   // 25,165,824 B
    __half* featsT_h = (__half*)(ws + 25165824);                      // 32,514,048 B
    float*  hiddenT  = (float*)(ws + 25165824 + 32514048);            //    262,144 B
    __half2* w2      = (__half2*)(ws + 25165824 + 32514048 + 262144); //      1,728 B
    __half2* b2      = (__half2*)(ws + 25165824 + 32514048 + 262144 + 1728); //  64 B

    prep_kernel<<<1, 512, 0, stream>>>(conv_w, conv_b, w2, b2);
    transpose_f16_kernel<<<dim3(CHW / 64, BATCH / 64), 256, 0, stream>>>(inputs, inT_h);
    conv_pool_kernel<<<dim3(21, 63), 256, 0, stream>>>((const __half2*)inT_h, w2, b2,
                                                       (__half2*)featsT_h);
    hidden_kernel<<<dim3(NH, 2), 1024, 0, stream>>>(featsT_h, hidden_i, hidden_w,
                                                    hidden_b, hiddenT);
    out_kernel<<<NO, 256, 0, stream>>>(hiddenT, out_w, out_b, out);
}

// Round 5
// 460.223 us; speedup vs baseline: 1.2598x; 1.2598x over previous
//
#include <hip/hip_runtime.h>
#include <hip/hip_fp16.h>
#include <math.h>

// Problem constants
#define BATCH 256
#define CIN 3
#define HW 128
#define OC 16
#define POOLED 63          // pooled spatial dim
#define FEAT 63504         // OC*63*63
#define NH 256
#define FANIN 512
#define NO 10
#define CHW (CIN*HW*HW)    // 49152

// packed f16 max — ROCm 7.2 lacks __hmax2 on gfx950; this pattern-matches to
// v_pk_max_f16.
__device__ inline __half2 h2max(__half2 a, __half2 b) {
    return __halves2half2(__hmax(__low2half(a),  __low2half(b)),
                          __hmax(__high2half(a), __high2half(b)));
}

// ---- Kernel 0: prep — duplicate conv weights/bias into __half2 {w,w} ----------
__global__ __launch_bounds__(512) void prep_kernel(const float* __restrict__ cw,
                                                   const float* __restrict__ cb,
                                                   __half2* __restrict__ w2,
                                                   __half2* __restrict__ b2) {
    const int t = threadIdx.x;
    if (t < OC * 27) {
        __half h = __float2half_rn(cw[t]);
        w2[t] = __halves2half2(h, h);
    } else if (t < OC * 27 + OC) {
        __half h = __float2half_rn(cb[t - OC * 27]);
        b2[t - OC * 27] = __halves2half2(h, h);
    }
}

// ---- Kernel 1: transpose+convert inputs (B, CHW) fp32 -> (CHW, B) f16 ----------
__global__ __launch_bounds__(256) void transpose_f16_kernel(const float* __restrict__ in,
                                                            __half* __restrict__ outh) {
    __shared__ float tile[64][65];   // tile[b_local][f_local]
    const int f0 = blockIdx.x * 64;
    const int b0 = blockIdx.y * 64;
    const int t  = threadIdx.x;
    // read phase: float4 along f, coalesced 256B/wave
    {
        const int r  = t >> 4;          // 0..15
        const int cg = t & 15;          // 0..15
#pragma unroll
        for (int it = 0; it < 4; ++it) {
            const int bl = r + 16 * it;
            const float4 v = *(const float4*)&in[(size_t)(b0 + bl) * CHW + f0 + cg * 4];
            tile[bl][cg * 4 + 0] = v.x;
            tile[bl][cg * 4 + 1] = v.y;
            tile[bl][cg * 4 + 2] = v.z;
            tile[bl][cg * 4 + 3] = v.w;
        }
    }
    __syncthreads();
    // write phase: each thread packs 8 b's (4 half2) for one f row -> 16B store
    {
        const int bg = t & 7;           // 8 groups of 8 b
#pragma unroll
        for (int it = 0; it < 2; ++it) {
            const int fl = (t >> 3) + 32 * it;   // 0..63
            __half2 hv[4];
            hv[0] = __floats2half2_rn(tile[bg * 8 + 0][fl], tile[bg * 8 + 1][fl]);
            hv[1] = __floats2half2_rn(tile[bg * 8 + 2][fl], tile[bg * 8 + 3][fl]);
            hv[2] = __floats2half2_rn(tile[bg * 8 + 4][fl], tile[bg * 8 + 5][fl]);
            hv[3] = __floats2half2_rn(tile[bg * 8 + 6][fl], tile[bg * 8 + 7][fl]);
            *(float4*)&outh[(size_t)(f0 + fl) * BATCH + b0 + bg * 8] = *(float4*)hv;
        }
    }
}

// ---- Kernel 2: conv3x3 + bias + relu + maxpool2x2, packed-f16 (2 batches/lane) --
// inT2: (C,H,W, B/2) half2. featsT2: (FEAT, B/2) half2.
// Block: pooled row i, 3 pooled cols; t&127 = batch-pair, t>>7 = oc-group (8 ocs).
// launch_bounds(256,4): VGPR cap 128 — (256,6) made the allocator spill the V
// patch to scratch (R4: VGPR=40, FETCH 972MB, WRITE 381MB, 466us).
__global__ __launch_bounds__(256, 4) void conv_pool_kernel(const __half2* __restrict__ inT2,
                                                           const __half2* __restrict__ w2,
                                                           const __half2* __restrict__ b2,
                                                           __half2* __restrict__ featsT2) {
    const int t  = threadIdx.x;
    const int bp = t & 127;         // batch pair 0..127
    const int og = t >> 7;          // 0..1 oc group
    const int i  = blockIdx.y;      // pooled row
    const int jt = blockIdx.x;      // tile of 3 pooled cols
    const int yb = 2 * i;
    const __half2 zero2 = __float2half2_rn(0.0f);

    for (int s = 0; s < 3; ++s) {
        const int j  = jt * 3 + s;
        const int x0 = 2 * j;       // input cols x0..x0+3
        __half2 V[CIN][4][4];
#pragma unroll
        for (int c = 0; c < CIN; ++c)
#pragma unroll
            for (int dy = 0; dy < 4; ++dy)
#pragma unroll
                for (int dx = 0; dx < 4; ++dx)
                    V[c][dy][dx] =
                        inT2[(size_t)((c * HW + (yb + dy)) * HW + (x0 + dx)) * 128 + bp];

#pragma unroll
        for (int o = 0; o < 8; ++o) {
            const int oc = og * 8 + o;
            __half2 a00 = zero2, a01 = zero2, a10 = zero2, a11 = zero2;
#pragma unroll
            for (int c = 0; c < CIN; ++c)
#pragma unroll
                for (int ky = 0; ky < 3; ++ky)
#pragma unroll
                    for (int kx = 0; kx < 3; ++kx) {
                        const __half2 w = w2[oc * 27 + c * 9 + ky * 3 + kx];
                        a00 = __hfma2(V[c][ky    ][kx    ], w, a00);
                        a01 = __hfma2(V[c][ky    ][kx + 1], w, a01);
                        a10 = __hfma2(V[c][ky + 1][kx    ], w, a10);
                        a11 = __hfma2(V[c][ky + 1][kx + 1], w, a11);
                    }
            __half2 m = h2max(h2max(a00, a01), h2max(a10, a11));
            __half2 r = h2max(__hadd2(m, b2[oc]), zero2);
            featsT2[(size_t)(oc * 3969 + i * POOLED + j) * 128 + bp] = r;
        }
    }
}

// ---- Kernel 3: sparse hidden layer, f16 feats, transposed ----------------------
// Grid (NH, 2): block = (h, b-half). 1024 threads = 8 k-splits x 128 b.
__global__ __launch_bounds__(1024) void hidden_kernel(const __half* __restrict__ featsT_h,
                                                      const int* __restrict__ hidx,
                                                      const float* __restrict__ hw,
                                                      const float* __restrict__ hb,
                                                      float* __restrict__ hiddenT) {
    __shared__ int   sidx[FANIN];
    __shared__ float swt[FANIN];
    __shared__ float red[1024];
    const int h  = blockIdx.x;
    const int bh = blockIdx.y;
    const int t  = threadIdx.x;
    if (t < FANIN) {
        sidx[t] = hidx[h * FANIN + t];
        swt[t]  = hw[h * FANIN + t];
    }
    __syncthreads();
    const int b  = bh * 128 + (t & 127);
    const int ks = t >> 7;          // 0..7
    const int k0 = ks * 64;
    float acc = 0.f;
#pragma unroll 16
    for (int kk = 0; kk < 64; ++kk) {
        const int k = k0 + kk;
        acc += __half2float(featsT_h[(size_t)sidx[k] * BATCH + b]) * swt[k];
    }
    red[t] = acc;
    __syncthreads();
    if (t < 128) {
        float s = ((red[t] + red[t + 128]) + (red[t + 256] + red[t + 384]))
                + ((red[t + 512] + red[t + 640]) + (red[t + 768] + red[t + 896]));
        s += hb[h];
        hiddenT[h * BATCH + bh * 128 + t] = 1.0f / (1.0f + __expf(-s));
    }
}

// ---- Kernel 4: dense 256->10 output layer --------------------------------------
__global__ __launch_bounds__(256) void out_kernel(const float* __restrict__ hiddenT,
                                                  const float* __restrict__ ow,
                                                  const float* __restrict__ ob,
                                                  float* __restrict__ out) {
    const int o = blockIdx.x;       // 0..9
    const int b = threadIdx.x;      // 0..255
    float a0 = 0.f, a1 = 0.f, a2 = 0.f, a3 = 0.f;
#pragma unroll 16
    for (int h = 0; h < NH; h += 4) {
        a0 += hiddenT[(h + 0) * BATCH + b] * ow[o * NH + h + 0];
        a1 += hiddenT[(h + 1) * BATCH + b] * ow[o * NH + h + 1];
        a2 += hiddenT[(h + 2) * BATCH + b] * ow[o * NH + h + 2];
        a3 += hiddenT[(h + 3) * BATCH + b] * ow[o * NH + h + 3];
    }
    float acc = (a0 + a1) + (a2 + a3);
    out[b * NO + o] = 1.0f / (1.0f + __expf(-(acc + ob[o])));
}

extern "C" void kernel_launch(void* const* d_in, const int* in_sizes, int n_in,
                              void* d_out, int out_size, void* d_ws, size_t ws_size,
                              hipStream_t stream) {
    const float* inputs   = (const float*)d_in[0];
    const float* conv_w   = (const float*)d_in[1];
    const float* conv_b   = (const float*)d_in[2];
    const int*   hidden_i = (const int*)d_in[3];
    const float* hidden_w = (const float*)d_in[4];
    const float* hidden_b = (const float*)d_in[5];
    const float* out_w    = (const float*)d_in[6];
    const float* out_b    = (const float*)d_in[7];
    float* out = (float*)d_out;

    char* ws = (char*)d_ws;
    __half* inT_h    = (__half*)ws;                                   // 25,165,824 B
    __half* featsT_h = (__half*)(ws + 25165824);                      // 32,514,048 B
    float*  hiddenT  = (float*)(ws + 25165824 + 32514048);            //    262,144 B
    __half2* w2      = (__half2*)(ws + 25165824 + 32514048 + 262144); //      1,728 B
    __half2* b2      = (__half2*)(ws + 25165824 + 32514048 + 262144 + 1728); //  64 B

    prep_kernel<<<1, 512, 0, stream>>>(conv_w, conv_b, w2, b2);
    transpose_f16_kernel<<<dim3(CHW / 64, BATCH / 64), 256, 0, stream>>>(inputs, inT_h);
    conv_pool_kernel<<<dim3(21, 63), 256, 0, stream>>>((const __half2*)inT_h, w2, b2,
                                                       (__half2*)featsT_h);
    hidden_kernel<<<dim3(NH, 2), 1024, 0, stream>>>(featsT_h, hidden_i, hidden_w,
                                                    hidden_b, hiddenT);
    out_kernel<<<NO, 256, 0, stream>>>(hiddenT, out_w, out_b, out);
}

// Round 6
// 221.625 us; speedup vs baseline: 2.6160x; 2.0766x over previous
//
#include <hip/hip_runtime.h>
#include <hip/hip_fp16.h>
#include <math.h>

// Problem constants
#define BATCH 256
#define CIN 3
#define HW 128
#define OC 16
#define POOLED 63          // pooled spatial dim
#define FEAT 63504         // OC*63*63
#define NH 256
#define FANIN 512
#define NO 10
#define CHW (CIN*HW*HW)    // 49152

// packed f16 max — ROCm 7.2 lacks __hmax2 on gfx950; pattern-matches to v_pk_max_f16.
__device__ inline __half2 h2max(__half2 a, __half2 b) {
    return __halves2half2(__hmax(__low2half(a),  __low2half(b)),
                          __hmax(__high2half(a), __high2half(b)));
}

// ---- Kernel 1: transpose+convert inputs (B, CHW) fp32 -> (CHW, B) f16 ----------
__global__ __launch_bounds__(256) void transpose_f16_kernel(const float* __restrict__ in,
                                                            __half* __restrict__ outh) {
    __shared__ float tile[64][65];   // tile[b_local][f_local]
    const int f0 = blockIdx.x * 64;
    const int b0 = blockIdx.y * 64;
    const int t  = threadIdx.x;
    // read phase: float4 along f, coalesced
    {
        const int r  = t >> 4;          // 0..15
        const int cg = t & 15;          // 0..15
#pragma unroll
        for (int it = 0; it < 4; ++it) {
            const int bl = r + 16 * it;
            const float4 v = *(const float4*)&in[(size_t)(b0 + bl) * CHW + f0 + cg * 4];
            tile[bl][cg * 4 + 0] = v.x;
            tile[bl][cg * 4 + 1] = v.y;
            tile[bl][cg * 4 + 2] = v.z;
            tile[bl][cg * 4 + 3] = v.w;
        }
    }
    __syncthreads();
    // write phase: pack 8 b's (4 half2) per f row -> 16B store
    {
        const int bg = t & 7;
#pragma unroll
        for (int it = 0; it < 2; ++it) {
            const int fl = (t >> 3) + 32 * it;   // 0..63
            __half2 hv[4];
            hv[0] = __floats2half2_rn(tile[bg * 8 + 0][fl], tile[bg * 8 + 1][fl]);
            hv[1] = __floats2half2_rn(tile[bg * 8 + 2][fl], tile[bg * 8 + 3][fl]);
            hv[2] = __floats2half2_rn(tile[bg * 8 + 4][fl], tile[bg * 8 + 5][fl]);
            hv[3] = __floats2half2_rn(tile[bg * 8 + 6][fl], tile[bg * 8 + 7][fl]);
            *(float4*)&outh[(size_t)(f0 + fl) * BATCH + b0 + bg * 8] = *(float4*)hv;
        }
    }
}

// ---- Kernel 2: conv3x3 + bias + relu + maxpool2x2, packed-f16 ------------------
// inT2: (C,H,W, B/2) half2. featsT2: (FEAT, B/2) half2.
// One block = one pooled pixel (i,j). 256 thr = 128 batch-pairs x 2 oc-groups.
// Weights live in LDS (wave-uniform ds_read broadcast) — keeping them in VGPRs
// is what caused the R5 spill (216 loop-invariant half2 hoisted; SGPR 112->32).
// No min-waves launch_bounds: both (256,6) and (256,4) triggered scratch spill.
__global__ __launch_bounds__(256) void conv_pool_kernel(const __half2* __restrict__ inT2,
                                                        const float* __restrict__ cw,
                                                        const float* __restrict__ cb,
                                                        __half2* __restrict__ featsT2) {
    __shared__ __half2 swb[448];    // [0..431] dup'd conv_w, [432..447] dup'd bias
    const int t = threadIdx.x;
    for (int idx = t; idx < 448; idx += 256) {
        const float f = (idx < 432) ? cw[idx] : cb[idx - 432];
        const __half h = __float2half_rn(f);
        swb[idx] = __halves2half2(h, h);
    }
    __syncthreads();

    const int bp = t & 127;         // batch pair
    const int og = t >> 7;          // 0..1, wave-uniform
    const int i  = blockIdx.y;      // pooled row
    const int j  = blockIdx.x;      // pooled col
    const int yb = 2 * i;
    const int x0 = 2 * j;
    const __half2 zero2 = __float2half2_rn(0.0f);

    __half2 acc[8][4];
#pragma unroll
    for (int o = 0; o < 8; ++o)
#pragma unroll
        for (int p = 0; p < 4; ++p) acc[o][p] = zero2;

    const __half2* base = inT2 + bp;
#pragma unroll
    for (int c = 0; c < CIN; ++c) {
        __half2 V[4][4];
#pragma unroll
        for (int dy = 0; dy < 4; ++dy)
#pragma unroll
            for (int dx = 0; dx < 4; ++dx)
                V[dy][dx] = base[(size_t)((c * HW + yb + dy) * HW + x0 + dx) * 128];

#pragma unroll
        for (int o = 0; o < 8; ++o) {
            const int oc = og * 8 + o;
            const __half2* wp = &swb[oc * 27 + c * 9];
#pragma unroll
            for (int ky = 0; ky < 3; ++ky)
#pragma unroll
                for (int kx = 0; kx < 3; ++kx) {
                    const __half2 w = wp[ky * 3 + kx];
                    acc[o][0] = __hfma2(V[ky    ][kx    ], w, acc[o][0]);
                    acc[o][1] = __hfma2(V[ky    ][kx + 1], w, acc[o][1]);
                    acc[o][2] = __hfma2(V[ky + 1][kx    ], w, acc[o][2]);
                    acc[o][3] = __hfma2(V[ky + 1][kx + 1], w, acc[o][3]);
                }
        }
    }

#pragma unroll
    for (int o = 0; o < 8; ++o) {
        const int oc = og * 8 + o;
        __half2 m = h2max(h2max(acc[o][0], acc[o][1]), h2max(acc[o][2], acc[o][3]));
        __half2 r = h2max(__hadd2(m, swb[432 + oc]), zero2);
        featsT2[(size_t)(oc * 3969 + i * POOLED + j) * 128 + bp] = r;
    }
}

// ---- Kernel 3: sparse hidden layer, f16 feats, transposed ----------------------
// Grid (NH, 2): block = (h, b-half). 1024 threads = 8 k-splits x 128 b.
__global__ __launch_bounds__(1024) void hidden_kernel(const __half* __restrict__ featsT_h,
                                                      const int* __restrict__ hidx,
                                                      const float* __restrict__ hw,
                                                      const float* __restrict__ hb,
                                                      float* __restrict__ hiddenT) {
    __shared__ int   sidx[FANIN];
    __shared__ float swt[FANIN];
    __shared__ float red[1024];
    const int h  = blockIdx.x;
    const int bh = blockIdx.y;
    const int t  = threadIdx.x;
    if (t < FANIN) {
        sidx[t] = hidx[h * FANIN + t];
        swt[t]  = hw[h * FANIN + t];
    }
    __syncthreads();
    const int b  = bh * 128 + (t & 127);
    const int ks = t >> 7;          // 0..7
    const int k0 = ks * 64;
    float acc = 0.f;
#pragma unroll 16
    for (int kk = 0; kk < 64; ++kk) {
        const int k = k0 + kk;
        acc += __half2float(featsT_h[(size_t)sidx[k] * BATCH + b]) * swt[k];
    }
    red[t] = acc;
    __syncthreads();
    if (t < 128) {
        float s = ((red[t] + red[t + 128]) + (red[t + 256] + red[t + 384]))
                + ((red[t + 512] + red[t + 640]) + (red[t + 768] + red[t + 896]));
        s += hb[h];
        hiddenT[h * BATCH + bh * 128 + t] = 1.0f / (1.0f + __expf(-s));
    }
}

// ---- Kernel 4: dense 256->10 output layer --------------------------------------
__global__ __launch_bounds__(256) void out_kernel(const float* __restrict__ hiddenT,
                                                  const float* __restrict__ ow,
                                                  const float* __restrict__ ob,
                                                  float* __restrict__ out) {
    const int o = blockIdx.x;       // 0..9
    const int b = threadIdx.x;      // 0..255
    float a0 = 0.f, a1 = 0.f, a2 = 0.f, a3 = 0.f;
#pragma unroll 16
    for (int h = 0; h < NH; h += 4) {
        a0 += hiddenT[(h + 0) * BATCH + b] * ow[o * NH + h + 0];
        a1 += hiddenT[(h + 1) * BATCH + b] * ow[o * NH + h + 1];
        a2 += hiddenT[(h + 2) * BATCH + b] * ow[o * NH + h + 2];
        a3 += hiddenT[(h + 3) * BATCH + b] * ow[o * NH + h + 3];
    }
    float acc = (a0 + a1) + (a2 + a3);
    out[b * NO + o] = 1.0f / (1.0f + __expf(-(acc + ob[o])));
}

extern "C" void kernel_launch(void* const* d_in, const int* in_sizes, int n_in,
                              void* d_out, int out_size, void* d_ws, size_t ws_size,
                              hipStream_t stream) {
    const float* inputs   = (const float*)d_in[0];
    const float* conv_w   = (const float*)d_in[1];
    const float* conv_b   = (const float*)d_in[2];
    const int*   hidden_i = (const int*)d_in[3];
    const float* hidden_w = (const float*)d_in[4];
    const float* hidden_b = (const float*)d_in[5];
    const float* out_w    = (const float*)d_in[6];
    const float* out_b    = (const float*)d_in[7];
    float* out = (float*)d_out;

    char* ws = (char*)d_ws;
    __half* inT_h    = (__half*)ws;                                   // 25,165,824 B
    __half* featsT_h = (__half*)(ws + 25165824);                      // 32,514,048 B
    float*  hiddenT  = (float*)(ws + 25165824 + 32514048);            //    262,144 B

    transpose_f16_kernel<<<dim3(CHW / 64, BATCH / 64), 256, 0, stream>>>(inputs, inT_h);
    conv_pool_kernel<<<dim3(POOLED, POOLED), 256, 0, stream>>>((const __half2*)inT_h,
                                                               conv_w, conv_b,
                                                               (__half2*)featsT_h);
    hidden_kernel<<<dim3(NH, 2), 1024, 0, stream>>>(featsT_h, hidden_i, hidden_w,
                                                    hidden_b, hiddenT);
    out_kernel<<<NO, 256, 0, stream>>>(hiddenT, out_w, out_b, out);
}